// Round 3
// 120.442 us; speedup vs baseline: 1.0513x; 1.0513x over previous
//
#include <hip/hip_runtime.h>

// QueryAndGroup: ball_query(r=0.2, ns=32) + group xyz (centered) + group features.
//   xyz      [8][16384][3] f32   d_in[0]
//   new_xyz  [8][1024][3]  f32   d_in[1]
//   features [8][64][16384] f32  d_in[2]
//   out      [8][67][1024][32] f32
//
// R6 history: SoA coords (xs/ys/zs in d_ws) fixed phase-1 line requests.
// R7 (resubmitted twice after GPU-acquisition timeouts): both kernels sit
// ~3x above their traffic floors with near-optimal byte patterns ->
// limiter = instruction issue / iteration latency, not bytes.
//   (a) transpose: scalar 4B/lane global reads -> f4 reads (4x fewer
//       read instructions, same LDS scheme, 65-pad keeps banks ~2-way).
//   (b) qg_main phase 1: f4-vectorized SoA scan, 256 pts/iter with 3+3
//       f4 loads and 4 ballots (was 128 pts with 6 scalar loads and 2
//       ballots). Index order preserved: point index = base + 4*lane + k,
//       slot = cnt + sum_k popc(mask_k & lanemask) + own-lane prefix.

#define N_PTS   16384
#define M_Q     1024
#define B_SZ    8
#define NSAMP   32
#define NCH     64
#define R2      0.04f
#define OUT_CH  (3 + NCH)

typedef float f4 __attribute__((ext_vector_type(4)));

// ---------- features [B][C][N] -> ft [B][N][C]; also xyz AoS -> SoA ----------
__global__ __launch_bounds__(256) void transpose_kernel(
    const float* __restrict__ feat, const float* __restrict__ xyz,
    float* __restrict__ ft,
    float* __restrict__ xs, float* __restrict__ ys, float* __restrict__ zs)
{
    __shared__ float tile[64][65];                 // +1 pad
    const int b   = blockIdx.x & 7;                // XCD swizzle: batch = blockIdx % 8
    const int n0  = (blockIdx.x >> 3) << 6;
    const int tid = threadIdx.x;
    const float* __restrict__ fb = feat + (size_t)b * NCH * N_PTS;
    float* __restrict__ tb       = ft   + ((size_t)b * N_PTS + n0) * NCH;

    // SoA coords for this 64-point tile (threads 0..63)
    if (xs && tid < 64) {
        const int p = n0 + tid;
        const float* src = xyz + ((size_t)b * N_PTS + p) * 3;
        xs[(size_t)b * N_PTS + p] = src[0];
        ys[(size_t)b * N_PTS + p] = src[1];
        zs[(size_t)b * N_PTS + p] = src[2];
    }

    // f4 reads: 4 channel-rows x 256B per wave-instr (was scalar 4B/lane).
#pragma unroll
    for (int j = 0; j < 4; ++j) {
        const int fidx = j * 256 + tid;            // 1024 f4 per 64x64 tile
        const int c = fidx >> 4;                   // 0..63
        const int q = fidx & 15;                   // f4 along n
        const f4 v = __builtin_nontemporal_load(
            (const f4*)&fb[(size_t)c * N_PTS + n0 + q * 4]);
        tile[c][q * 4 + 0] = v.x;                  // banks (c + 4q + i): ~2-way, free
        tile[c][q * 4 + 1] = v.y;
        tile[c][q * 4 + 2] = v.z;
        tile[c][q * 4 + 3] = v.w;
    }
    __syncthreads();
    const int c4 = tid & 15;
    const int r  = tid >> 4;
#pragma unroll
    for (int j = 0; j < 4; ++j) {                  // write: 1KB dwordx4 per instr
        const int nn = j * 16 + r;
        f4 o;
        o.x = tile[c4 * 4 + 0][nn];
        o.y = tile[c4 * 4 + 1][nn];
        o.z = tile[c4 * 4 + 2][nn];
        o.w = tile[c4 * 4 + 3][nn];
        *(f4*)(&tb[(size_t)nn * NCH + c4 * 4]) = o;  // re-read later: keep cached
    }
}

// ---------- main: ball query + grouped gather. SOA: coords from xs/ys/zs ----------
// 4 waves/block, one query per wave, NO __syncthreads (all LDS per-wave).
template <bool SOA>
__global__ __launch_bounds__(256) void qg_main(
    const float* __restrict__ xyz,      // [B][N][3]
    const float* __restrict__ new_xyz,  // [B][M][3]
    const float* __restrict__ ft,       // [B][N][C]
    const float* __restrict__ xs, const float* __restrict__ ys,
    const float* __restrict__ zs,
    float* __restrict__ out)            // [B][67][M][NS]
{
    const int tid  = threadIdx.x;
    const int w    = tid >> 6;
    const int lane = tid & 63;
    const int b    = blockIdx.x & 7;               // XCD swizzle
    const int m    = ((blockIdx.x >> 3) << 2) + w;
    const int q    = (b << 10) + m;

    __shared__ float pxyz[4][NSAMP][4];            // [wave][slot] = {x, y, z, bits(idx)}
    __shared__ float tile[4][32][33];              // [wave][c_local][s]

    const float cx = new_xyz[q * 3 + 0];
    const float cy = new_xyz[q * 3 + 1];
    const float cz = new_xyz[q * 3 + 2];
    const float* __restrict__ xb = xyz + (size_t)b * N_PTS * 3;
    const unsigned long long lmask = (1ull << lane) - 1ull;
    int cnt = 0;

    if constexpr (SOA) {
        // ---- Phase 1 (SOA): f4 scan, 256 points/iter, software-pipelined ----
        const f4* __restrict__ xs4 = (const f4*)(xs + (size_t)b * N_PTS);
        const f4* __restrict__ ys4 = (const f4*)(ys + (size_t)b * N_PTS);
        const f4* __restrict__ zs4 = (const f4*)(zs + (size_t)b * N_PTS);

        f4 X = xs4[lane], Y = ys4[lane], Z = zs4[lane];   // points 4*lane..4*lane+3

        for (int base = 0; ; base += 256) {
            // prefetch next 256 points before this iteration's ballots
            const int  nbase = base + 256;
            const bool more  = nbase < N_PTS;
            const int  pidx  = more ? (nbase >> 2) + lane : lane;  // dummy: L1 hit
            const f4 NX = xs4[pidx], NY = ys4[pidx], NZ = zs4[pidx];

            float d2k[4];
#pragma unroll
            for (int k = 0; k < 4; ++k) {
                const float dx = __fsub_rn(cx, X[k]);
                const float dy = __fsub_rn(cy, Y[k]);
                const float dz = __fsub_rn(cz, Z[k]);
                d2k[k] = __fadd_rn(__fadd_rn(__fmul_rn(dx, dx), __fmul_rn(dy, dy)),
                                   __fmul_rn(dz, dz));
            }
            const bool h0 = d2k[0] < R2, h1 = d2k[1] < R2;
            const bool h2 = d2k[2] < R2, h3 = d2k[3] < R2;
            const unsigned long long m0 = __ballot(h0);
            const unsigned long long m1 = __ballot(h1);
            const unsigned long long m2 = __ballot(h2);
            const unsigned long long m3 = __ballot(h3);

            // hits at strictly smaller point index in this chunk:
            //   all sub-k of lanes < me  +  my own sub-k' < k
            const int P = (int)(__popcll(m0 & lmask) + __popcll(m1 & lmask) +
                                __popcll(m2 & lmask) + __popcll(m3 & lmask));
            int own = 0;
            const bool hk[4] = {h0, h1, h2, h3};
#pragma unroll
            for (int k = 0; k < 4; ++k) {
                if (hk[k]) {
                    const int slot = cnt + P + own;
                    if (slot < NSAMP) {
                        pxyz[w][slot][0] = X[k];
                        pxyz[w][slot][1] = Y[k];
                        pxyz[w][slot][2] = Z[k];
                        pxyz[w][slot][3] = __int_as_float(base + lane * 4 + k);
                    }
                }
                own += hk[k] ? 1 : 0;
            }
            cnt += (int)(__popcll(m0) + __popcll(m1) + __popcll(m2) + __popcll(m3));

            if (cnt >= NSAMP || !more) break;
            X = NX; Y = NY; Z = NZ;
        }
    } else {
        // ---- Phase 1 (AoS fallback): 2x64 scalar chunks, pipelined ----
        float Ax = xb[lane * 3 + 0], Ay = xb[lane * 3 + 1], Az = xb[lane * 3 + 2];
        float Bx = xb[(64 + lane) * 3 + 0], By = xb[(64 + lane) * 3 + 1],
              Bz = xb[(64 + lane) * 3 + 2];

        for (int base = 0; ; base += 128) {
            const int  nbase = base + 128;
            const bool more  = nbase < N_PTS;
            const int  pA = more ? nbase + lane : lane;
            const int  pB = pA + 64;
            const float nAx = xb[pA * 3 + 0], nAy = xb[pA * 3 + 1], nAz = xb[pA * 3 + 2];
            const float nBx = xb[pB * 3 + 0], nBy = xb[pB * 3 + 1], nBz = xb[pB * 3 + 2];

            {
                const float dx = __fsub_rn(cx, Ax), dy = __fsub_rn(cy, Ay), dz = __fsub_rn(cz, Az);
                const float d2 = __fadd_rn(__fadd_rn(__fmul_rn(dx, dx), __fmul_rn(dy, dy)),
                                           __fmul_rn(dz, dz));
                const bool hit = d2 < R2;
                const unsigned long long mk = __ballot(hit);
                if (hit) {
                    const int slot = cnt + __popcll(mk & lmask);
                    if (slot < NSAMP) {
                        pxyz[w][slot][0] = Ax; pxyz[w][slot][1] = Ay;
                        pxyz[w][slot][2] = Az; pxyz[w][slot][3] = __int_as_float(base + lane);
                    }
                }
                cnt += (int)__popcll(mk);
            }
            {
                const float dx = __fsub_rn(cx, Bx), dy = __fsub_rn(cy, By), dz = __fsub_rn(cz, Bz);
                const float d2 = __fadd_rn(__fadd_rn(__fmul_rn(dx, dx), __fmul_rn(dy, dy)),
                                           __fmul_rn(dz, dz));
                const bool hit = d2 < R2;
                const unsigned long long mk = __ballot(hit);
                if (hit) {
                    const int slot = cnt + __popcll(mk & lmask);
                    if (slot < NSAMP) {
                        pxyz[w][slot][0] = Bx; pxyz[w][slot][1] = By;
                        pxyz[w][slot][2] = Bz; pxyz[w][slot][3] = __int_as_float(base + 64 + lane);
                    }
                }
                cnt += (int)__popcll(mk);
            }
            if (cnt >= NSAMP || !more) break;
            Ax = nAx; Ay = nAy; Az = nAz;
            Bx = nBx; By = nBy; Bz = nBz;
        }
    }

    // fill empty slots with slot 0 (reference broadcasts sorted_idx[...,0])
    if (lane < NSAMP && cnt < NSAMP) {
        float v0x, v0y, v0z, v0w;
        if (cnt > 0) {
            v0x = pxyz[w][0][0]; v0y = pxyz[w][0][1];
            v0z = pxyz[w][0][2]; v0w = pxyz[w][0][3];
        } else {
            v0x = xb[0]; v0y = xb[1]; v0z = xb[2]; v0w = __int_as_float(0);
        }
        if (lane >= cnt) {
            pxyz[w][lane][0] = v0x; pxyz[w][lane][1] = v0y;
            pxyz[w][lane][2] = v0z; pxyz[w][lane][3] = v0w;
        }
    }
    // wave-synchronous: same-wave ds_write -> ds_read ordered by lgkmcnt

    float* __restrict__ ob = out + ((size_t)b * OUT_CH * M_Q + (size_t)m) * NSAMP;

    // ---- Phase 2a: centered xyz channels straight from LDS (24 lanes, 1 dwordx4) ----
    if (lane < 24) {
        const int c  = lane >> 3;        // 0..2
        const int s4 = lane & 7;
        const float ctr = (c == 0) ? cx : ((c == 1) ? cy : cz);
        f4 o;
        o.x = __fsub_rn(pxyz[w][s4 * 4 + 0][c], ctr);
        o.y = __fsub_rn(pxyz[w][s4 * 4 + 1][c], ctr);
        o.z = __fsub_rn(pxyz[w][s4 * 4 + 2][c], ctr);
        o.w = __fsub_rn(pxyz[w][s4 * 4 + 3][c], ctr);
        __builtin_nontemporal_store(o, (f4*)&ob[(size_t)c * (M_Q * NSAMP) + s4 * 4]);
    }

    // ---- Phase 2b: feature rows (256B contiguous), LDS transpose, dwordx4 nt stores ----
    const float* __restrict__ ftb = ft + (size_t)b * N_PTS * NCH;
    const int sgrp = lane >> 3;          // 0..7
    const int c4   = lane & 7;           // float4 within 32-ch chunk

#pragma unroll
    for (int chunk = 0; chunk < 2; ++chunk) {
        f4 vals[4];
#pragma unroll
        for (int i = 0; i < 4; ++i) {    // 8 lanes x 128B per row-half
            const int s = i * 8 + sgrp;
            const int n = __float_as_int(pxyz[w][s][3]);
            vals[i] = *(const f4*)(ftb + (size_t)n * NCH + chunk * 32 + c4 * 4);
        }
#pragma unroll
        for (int i = 0; i < 4; ++i) {    // [s][c] -> [c][s]  (<=2-way banks: free)
            const int s = i * 8 + sgrp;
            tile[w][c4 * 4 + 0][s] = vals[i].x;
            tile[w][c4 * 4 + 1][s] = vals[i].y;
            tile[w][c4 * 4 + 2][s] = vals[i].z;
            tile[w][c4 * 4 + 3][s] = vals[i].w;
        }
#pragma unroll
        for (int j = 0; j < 4; ++j) {    // 1KB nt store per instr
            const int c_loc = j * 8 + (lane >> 3);
            const int s4    = lane & 7;
            f4 o;
            o.x = tile[w][c_loc][s4 * 4 + 0];
            o.y = tile[w][c_loc][s4 * 4 + 1];
            o.z = tile[w][c_loc][s4 * 4 + 2];
            o.w = tile[w][c_loc][s4 * 4 + 3];
            __builtin_nontemporal_store(
                o, (f4*)&ob[(size_t)(3 + chunk * 32 + c_loc) * (M_Q * NSAMP) + s4 * 4]);
        }
    }
}

// ---------- fallback (ws too small): direct-gather kernel ----------
__global__ __launch_bounds__(256) void qg_fallback(
    const float* __restrict__ xyz, const float* __restrict__ new_xyz,
    const float* __restrict__ feat, float* __restrict__ out)
{
    const int tid  = threadIdx.x;
    const int w    = tid >> 6;
    const int lane = tid & 63;
    const int q    = blockIdx.x * 4 + w;
    const int b    = q >> 10;
    const int m    = q & (M_Q - 1);

    __shared__ int idx_sh[4][NSAMP];

    const float cx = new_xyz[q * 3 + 0];
    const float cy = new_xyz[q * 3 + 1];
    const float cz = new_xyz[q * 3 + 2];
    const float* __restrict__ xb = xyz + (size_t)b * N_PTS * 3;

    int cnt = 0;
    for (int base = 0; base < N_PTS && cnt < NSAMP; base += 64) {
        const int n = base + lane;
        const float dx = __fsub_rn(cx, xb[n * 3 + 0]);
        const float dy = __fsub_rn(cy, xb[n * 3 + 1]);
        const float dz = __fsub_rn(cz, xb[n * 3 + 2]);
        const float d2 = __fadd_rn(__fadd_rn(__fmul_rn(dx, dx), __fmul_rn(dy, dy)),
                                   __fmul_rn(dz, dz));
        const bool hit = d2 < R2;
        const unsigned long long mk = __ballot(hit);
        if (hit) {
            const int slot = cnt + __popcll(mk & ((1ull << lane) - 1ull));
            if (slot < NSAMP) idx_sh[w][slot] = n;
        }
        cnt += (int)__popcll(mk);
    }
    __syncthreads();
    if (lane < NSAMP) {
        const int v0 = (cnt > 0) ? idx_sh[w][0] : 0;
        if (lane >= cnt) idx_sh[w][lane] = v0;
    }
    __syncthreads();

    const float* __restrict__ fb = feat + (size_t)b * NCH * N_PTS;
    float* __restrict__ ob = out + ((size_t)b * OUT_CH * M_Q + (size_t)m) * NSAMP;
    for (int e = lane; e < OUT_CH * NSAMP; e += 64) {
        const int c = e >> 5, s = e & 31;
        const int n = idx_sh[w][s];
        float v;
        if (c < 3) {
            const float ctr = (c == 0) ? cx : ((c == 1) ? cy : cz);
            v = __fsub_rn(xb[n * 3 + c], ctr);
        } else {
            v = fb[(size_t)(c - 3) * N_PTS + n];
        }
        ob[(size_t)c * (M_Q * NSAMP) + s] = v;
    }
}

extern "C" void kernel_launch(void* const* d_in, const int* in_sizes, int n_in,
                              void* d_out, int out_size, void* d_ws, size_t ws_size,
                              hipStream_t stream) {
    const float* xyz     = (const float*)d_in[0];
    const float* new_xyz = (const float*)d_in[1];
    const float* feat    = (const float*)d_in[2];
    float* out           = (float*)d_out;

    const size_t ft_elems  = (size_t)B_SZ * N_PTS * NCH;        // 8388608
    const size_t soa_elems = (size_t)B_SZ * N_PTS;              // 131072
    const size_t need_soa  = (ft_elems + 3 * soa_elems) * sizeof(float);  // ~35.1 MB
    const size_t need_ft   = ft_elems * sizeof(float);                    // 33.6 MB

    float* ft = (float*)d_ws;
    float* xs = ft + ft_elems;
    float* ys = xs + soa_elems;
    float* zs = ys + soa_elems;

    if (ws_size >= need_soa) {
        transpose_kernel<<<B_SZ * (N_PTS / 64), 256, 0, stream>>>(feat, xyz, ft, xs, ys, zs);
        qg_main<true><<<(B_SZ * M_Q) / 4, 256, 0, stream>>>(
            xyz, new_xyz, ft, xs, ys, zs, out);
    } else if (ws_size >= need_ft) {
        transpose_kernel<<<B_SZ * (N_PTS / 64), 256, 0, stream>>>(
            feat, xyz, ft, nullptr, nullptr, nullptr);
        qg_main<false><<<(B_SZ * M_Q) / 4, 256, 0, stream>>>(
            xyz, new_xyz, ft, nullptr, nullptr, nullptr, out);
    } else {
        qg_fallback<<<(B_SZ * M_Q) / 4, 256, 0, stream>>>(xyz, new_xyz, feat, out);
    }
}